// Round 7
// baseline (450.354 us; speedup 1.0000x reference)
//
#include <hip/hip_runtime.h>
#include <hip/hip_bf16.h>

// ---------------------------------------------------------------------------
// PointCloudExtractor: T-Net -> transform -> multi-radius topK gather -> MLP
// B=8 N=2048 K=64 TU=256 U=512, blocks 512->512, 512->256, 256->170
// Pipeline: init(memset+convw_t+tnet1), tnet2, topk, mlp_k (all 5 layers)
// R2: topk insertion shift via DPP WF_SR1
// R6: fused init; topk 512-thr blocks
// R7: MLP row-fused: one block carries a 64-row stripe through all 5 layers;
//     activations ping-pong in LDS (2 x 64x512 bf16, XOR-swizzled), weights
//     read from L2 per block, barrier-free K-loops, operand-swapped MFMA
//     (A=weight rows, B=act rows -> lane holds 4 consecutive n for fixed m
//     -> ds_write_b64 stores + float4 BN loads). Eliminates ~130MB of
//     inter-layer HBM round trips and the 4 extra GEMM dispatches.
// ---------------------------------------------------------------------------

#define BN_SCALE 0.99950037468777f   // float32(1/sqrt(1+1e-3))

typedef short short8 __attribute__((ext_vector_type(8)));
typedef short sh4 __attribute__((ext_vector_type(4)));
typedef float floatx4 __attribute__((ext_vector_type(4)));

__device__ inline short f2bf(float x) {
    __hip_bfloat16 h = __float2bfloat16(x);
    return *reinterpret_cast<short*>(&h);
}
__device__ inline float bf2f(short s) {
    return __uint_as_float(((unsigned)(unsigned short)s) << 16);
}

// workspace layout (bytes)
#define OFF_FEATS 0                      // bf16 [16384,576]  18,874,368
#define OFF_W     18874368
#define OFF_C1WT  (OFF_W)                // bf16 [512][576]
#define OFF_RWT   (OFF_C1WT + 589824)    // bf16 [512][512]
#define OFF_B1WT  (OFF_RWT + 524288)     // bf16 [512][512]
#define OFF_B2WT  (OFF_B1WT + 524288)    // bf16 [256][512]
#define OFF_B3WT  (OFF_B2WT + 262144)    // bf16 [256][256] (rows>=170 zero)
#define OFF_PTS   (OFF_B3WT + 131072)    // f32 [8,2048,3]
#define OFF_PART  (OFF_PTS + 196608)     // f32 [8][8][256] tnet1 partial max

// ---- fused init: weight transpose (blocks 0..247) + T-Net layer1 partial
//      max (blocks 248..311) + d_out zero-init (block 312) -----------------
__global__ __launch_bounds__(256)
void init_k(const float* __restrict__ c1w, const float* __restrict__ rw,
            const float* __restrict__ b1w, const float* __restrict__ b2w,
            const float* __restrict__ b3w,
            short* __restrict__ c1wT, short* __restrict__ rwT,
            short* __restrict__ b1wT, short* __restrict__ b2wT,
            short* __restrict__ b3wT,
            const float* __restrict__ points, const float* __restrict__ tw,
            const float* __restrict__ tb, const float* __restrict__ tg1,
            const float* __restrict__ tbt1, float* __restrict__ part,
            float* __restrict__ outF, int out_n) {
    __shared__ float smem[64 * 65];
    const int bid = blockIdx.x;
    if (bid < 248) {
        float (*tile)[65] = (float(*)[65])smem;
        const float* src; short* dst; int K, N, t;
        if (bid < 72)       { src = c1w; dst = c1wT; K = 576; N = 512; t = bid; }
        else if (bid < 136) { src = rw;  dst = rwT;  K = 512; N = 512; t = bid - 72; }
        else if (bid < 200) { src = b1w; dst = b1wT; K = 512; N = 512; t = bid - 136; }
        else if (bid < 232) { src = b2w; dst = b2wT; K = 512; N = 256; t = bid - 200; }
        else                { src = b3w; dst = b3wT; K = 256; N = 170; t = bid - 232; }
        int ktiles = K >> 6;
        int k0 = (t % ktiles) * 64, n0 = (t / ktiles) * 64;
        int tx = threadIdx.x & 63, ty = threadIdx.x >> 6;
#pragma unroll
        for (int p = 0; p < 16; p++) {
            int r = p * 4 + ty;
            int n = n0 + tx;
            tile[r][tx] = (n < N) ? src[(size_t)(k0 + r) * N + n] : 0.f;
        }
        __syncthreads();
#pragma unroll
        for (int p = 0; p < 16; p++) {
            int r = p * 4 + ty;
            dst[(size_t)(n0 + r) * K + k0 + tx] = f2bf(tile[tx][r]);
        }
    } else if (bid < 312) {
        float* spts = smem;   // [768]
        const int t2 = bid - 248;
        const int chunk = t2 & 7, b = t2 >> 3;
        const int u = threadIdx.x;
        const float* pb = points + ((size_t)b * 2048 + chunk * 256) * 3;
        for (int i = u; i < 768; i += 256) spts[i] = pb[i];
        const float w0 = tw[u], w1 = tw[256 + u], w2 = tw[512 + u];
        const float bi = tb[u];
        const float gs = tg1[u] * BN_SCALE, bt = tbt1[u];
        __syncthreads();
        float m = 0.f;  // relu outputs >= 0
        for (int nn = 0; nn < 256; nn++) {
            float v = spts[nn * 3] * w0 + spts[nn * 3 + 1] * w1 +
                      spts[nn * 3 + 2] * w2 + bi;
            v = fmaxf(v * gs + bt, 0.f);
            m = fmaxf(m, v);
        }
        part[((b * 8 + chunk) << 8) + u] = m;
    } else {
        for (int i = threadIdx.x; i < out_n; i += 256) outF[i] = 0.f;
    }
}

// ---- T-Net dense layers + transform pts (latency-parallel matvecs) ---------
__global__ __launch_bounds__(1024)
void tnet2_k(const float* __restrict__ points, const float* __restrict__ part,
             const float* __restrict__ td1w, const float* __restrict__ td1b,
             const float* __restrict__ tg2, const float* __restrict__ tbt2,
             const float* __restrict__ td2w, const float* __restrict__ td2b,
             float* __restrict__ pts_out) {
    __shared__ float sx[256], sp[4][256], sx2[256], sp2[9][32], sT[9];
    const int b = blockIdx.x;
    const int tid = threadIdx.x;
    if (tid < 256) {
        float m = 0.f;
#pragma unroll
        for (int c = 0; c < 8; c++) m = fmaxf(m, part[((b * 8 + c) << 8) + tid]);
        sx[tid] = m;
    }
    __syncthreads();
    {
        int t = tid & 255, g = tid >> 8;
        float s = 0.f;
#pragma unroll 8
        for (int i = 0; i < 64; i++) {
            int v = g * 64 + i;
            s += sx[v] * td1w[v * 256 + t];
        }
        sp[g][t] = s;
    }
    __syncthreads();
    if (tid < 256) {
        float s = td1b[tid] + sp[0][tid] + sp[1][tid] + sp[2][tid] + sp[3][tid];
        sx2[tid] = fmaxf(s * (tg2[tid] * BN_SCALE) + tbt2[tid], 0.f);
    }
    __syncthreads();
    if (tid < 288) {
        int j = tid / 32, vg = tid & 31;
        float s = 0.f;
#pragma unroll
        for (int i = 0; i < 8; i++) {
            int v = vg * 8 + i;
            s += sx2[v] * td2w[v * 9 + j];
        }
        sp2[j][vg] = s;
    }
    __syncthreads();
    if (tid < 9) {
        float s = td2b[tid];
        for (int vg = 0; vg < 32; vg++) s += sp2[tid][vg];
        sT[tid] = s;
    }
    __syncthreads();
    for (int n = tid; n < 2048; n += 1024) {
        size_t idx = ((size_t)b * 2048 + n) * 3;
        float p0 = points[idx], p1 = points[idx + 1], p2 = points[idx + 2];
        pts_out[idx]     = p0 * sT[0] + p1 * sT[3] + p2 * sT[6];
        pts_out[idx + 1] = p0 * sT[1] + p1 * sT[4] + p2 * sT[7];
        pts_out[idx + 2] = p0 * sT[2] + p1 * sT[5] + p2 * sT[8];
    }
}

// ---- top-K ball query + gather -> feats bf16 (R6-verified) -----------------
__device__ inline unsigned dpp_shr1(unsigned v) {
    return (unsigned)__builtin_amdgcn_update_dpp(0, (int)v, 0x138 /*WF_SR1*/,
                                                 0xF, 0xF, false);
}

__device__ inline void ins_one(unsigned& llo, unsigned& lhi, unsigned vlo,
                               unsigned vhi, int lane) {
    unsigned long long lv = ((unsigned long long)lhi << 32) | llo;
    unsigned long long vv = ((unsigned long long)vhi << 32) | vlo;
    unsigned long long ltm = __ballot(lv < vv);
    if (ltm) {
        int p = __builtin_ctzll(ltm);
        unsigned uplo = dpp_shr1(llo);
        unsigned uphi = dpp_shr1(lhi);
        if (lane >= p) {
            llo = (lane == p) ? vlo : uplo;
            lhi = (lane == p) ? vhi : uphi;
        }
    }
}

__device__ inline void run_q(unsigned& llo, unsigned& lhi, unsigned long long& th,
                             unsigned klo, unsigned khi, unsigned long long qual,
                             int lane) {
    do {
        int src = __builtin_ctzll(qual);
        qual &= qual - 1;
        unsigned vlo = (unsigned)__builtin_amdgcn_readlane((int)klo, src);
        unsigned vhi = (unsigned)__builtin_amdgcn_readlane((int)khi, src);
        ins_one(llo, lhi, vlo, vhi, lane);
    } while (qual);
    th = ((unsigned long long)(unsigned)__builtin_amdgcn_readlane((int)lhi, 63) << 32)
         | (unsigned)__builtin_amdgcn_readlane((int)llo, 63);
}

__device__ inline void init_radius(bool in, unsigned nb, unsigned klo, int lane,
                                   unsigned& llo, unsigned& lhi,
                                   unsigned long long& th) {
    unsigned long long inm = __ballot(in);
    int S = 64 - __builtin_popcountll(inm);
    int mbI = __builtin_amdgcn_mbcnt_hi((unsigned)(inm >> 32),
              __builtin_amdgcn_mbcnt_lo((unsigned)inm, 0));
    int mbS = lane - mbI;
    int dst = in ? (S + mbI) : mbS;
    llo = (unsigned)__builtin_amdgcn_ds_permute(dst << 2, in ? 0 : (int)klo);
    lhi = 0;
    if (inm) {
        do {
            int src = __builtin_ctzll(inm);
            inm &= inm - 1;
            unsigned vlo = (unsigned)__builtin_amdgcn_readlane((int)klo, src);
            unsigned vhi = (unsigned)__builtin_amdgcn_readlane((int)nb, src);
            ins_one(llo, lhi, vlo, vhi, lane);
        } while (inm);
    }
    th = ((unsigned long long)(unsigned)__builtin_amdgcn_readlane((int)lhi, 63) << 32)
         | (unsigned)__builtin_amdgcn_readlane((int)llo, 63);
}

__global__ __launch_bounds__(512)
void topk_feats_k(const float* __restrict__ pts, const float* __restrict__ noise,
                  short* __restrict__ feats) {
    __shared__ float sxp[2048], syp[2048], szp[2048];
    const int b = blockIdx.y;
    const int tid = threadIdx.x;
    const int lane = tid & 63;
    const int wave = tid >> 6;
    const int n = blockIdx.x * 8 + wave;
    const float* nrow = noise + ((size_t)b * 2048 + n) * 2048;
    float ncur = nrow[lane];
    float nnxt = nrow[64 + lane];
    for (int i = tid; i < 2048; i += 512) {
        size_t p = ((size_t)b * 2048 + i) * 3;
        sxp[i] = pts[p];
        syp[i] = pts[p + 1];
        szp[i] = pts[p + 2];
    }
    __syncthreads();
    const float qx = sxp[n], qy = syp[n], qz = szp[n];

    unsigned L0lo, L0hi, L1lo, L1hi, L2lo, L2hi;
    unsigned long long th0, th1, th2;
    {
        float dx = qx - sxp[lane], dy = qy - syp[lane], dz = qz - szp[lane];
        float d = sqrtf(dx * dx + dy * dy + dz * dz);
        unsigned nb = __float_as_uint(ncur);
        unsigned klo = 2047 - lane;
        init_radius(d <= 0.1f, nb, klo, lane, L0lo, L0hi, th0);
        init_radius(d <= 0.3f, nb, klo, lane, L1lo, L1hi, th1);
        init_radius(d <= 0.7f, nb, klo, lane, L2lo, L2hi, th2);
    }
    for (int base = 64; base < 2048; base += 64) {
        float cur = nnxt;
        if (base + 64 < 2048) nnxt = nrow[base + 64 + lane];
        const int j = base + lane;
        float dx = qx - sxp[j], dy = qy - syp[j], dz = qz - szp[j];
        float d = sqrtf(dx * dx + dy * dy + dz * dz);
        unsigned nb = __float_as_uint(cur);
        unsigned klo = 2047 - j;
        unsigned k0hi = (d <= 0.1f) ? nb : 0u;
        unsigned k1hi = (d <= 0.3f) ? nb : 0u;
        unsigned k2hi = (d <= 0.7f) ? nb : 0u;
        unsigned long long key0 = ((unsigned long long)k0hi << 32) | klo;
        unsigned long long key1 = ((unsigned long long)k1hi << 32) | klo;
        unsigned long long key2 = ((unsigned long long)k2hi << 32) | klo;
        unsigned long long q0 = __ballot(key0 > th0);
        unsigned long long q1 = __ballot(key1 > th1);
        unsigned long long q2 = __ballot(key2 > th2);
        if (q0) run_q(L0lo, L0hi, th0, klo, k0hi, q0, lane);
        if (q1) run_q(L1lo, L1hi, th1, klo, k1hi, q1, lane);
        if (q2) run_q(L2lo, L2hi, th2, klo, k2hi, q2, lane);
    }
    size_t basef = ((size_t)b * 2048 + n) * 576 + (size_t)lane * 9;
    int j0 = 2047 - (int)(L0lo & 0x7FFu);
    int j1 = 2047 - (int)(L1lo & 0x7FFu);
    int j2 = 2047 - (int)(L2lo & 0x7FFu);
    feats[basef + 0] = f2bf(sxp[j0]);
    feats[basef + 1] = f2bf(syp[j0]);
    feats[basef + 2] = f2bf(szp[j0]);
    feats[basef + 3] = f2bf(sxp[j1]);
    feats[basef + 4] = f2bf(syp[j1]);
    feats[basef + 5] = f2bf(szp[j1]);
    feats[basef + 6] = f2bf(sxp[j2]);
    feats[basef + 7] = f2bf(syp[j2]);
    feats[basef + 8] = f2bf(szp[j2]);
}

// ---- row-fused MLP ---------------------------------------------------------
// One block = 64-row stripe through all 5 layers. Activations in LDS
// ping-pong buffers [64][512] bf16, XOR-swizzled (byte ^= (row&7)<<4) to
// kill the stride-1024B bank conflict on fragment reads.
// Operand-swapped MFMA: A-operand = weight rows (WT[n][k], global/L2),
// B-operand = act rows (LDS). D-frag: lane holds n = n0w+i*16+lq*4+rg
// (4 consecutive n), m = j*16+lr -> 8B ds_write_b64 stores, float4 BN loads.
// Load mapping (verified structure): af[i] row = i*16+lr, k = lq*8.
// EPI 0: relu(bn(acc+bias)) -> act | EPI 1: acc+bias+resid -> act
// EPI 2: relu(bn(acc+bias)) -> col-max over m, atomicMax into out
template <int NF, int EPI, int BSRC, int K>
__device__ __forceinline__ void layer(
    const short* __restrict__ WT, const short* __restrict__ gfeats,
    const short* actIn, short* actOut,
    const float* __restrict__ bias, const float* __restrict__ gamma,
    const float* __restrict__ beta, float* __restrict__ outF,
    int m0, int Nact) {
    const int tid = threadIdx.x;
    const int lane = tid & 63;
    const int wave = tid >> 6;
    const int lr = lane & 15, lq = lane >> 4;
    const int n0w = wave * (NF * 16);

    floatx4 acc[NF][4];
#pragma unroll
    for (int i = 0; i < NF; i++)
#pragma unroll
        for (int j = 0; j < 4; j++) acc[i][j] = (floatx4){0.f, 0.f, 0.f, 0.f};

#pragma unroll 2
    for (int k0 = 0; k0 < K; k0 += 32) {
        short8 af[NF], bf[4];
#pragma unroll
        for (int i = 0; i < NF; i++)
            af[i] = *(const short8*)(WT + (size_t)(n0w + i * 16 + lr) * K + k0 + lq * 8);
        if (BSRC == 0) {
#pragma unroll
            for (int j = 0; j < 4; j++)
                bf[j] = *(const short8*)(gfeats + (size_t)(m0 + j * 16 + lr) * 576 + k0 + lq * 8);
        } else {
#pragma unroll
            for (int j = 0; j < 4; j++) {
                int m = j * 16 + lr;
                bf[j] = *(const short8*)((const char*)actIn + m * 1024 +
                                         ((k0 * 2 + lq * 16) ^ ((m & 7) << 4)));
            }
        }
#pragma unroll
        for (int i = 0; i < NF; i++)
#pragma unroll
            for (int j = 0; j < 4; j++)
                acc[i][j] = __builtin_amdgcn_mfma_f32_16x16x32_bf16(af[i], bf[j],
                                                                    acc[i][j], 0, 0, 0);
    }

    if (EPI == 2) {
        const int bb = m0 >> 11;
#pragma unroll
        for (int i = 0; i < NF; i++) {
            int nb = n0w + i * 16 + lq * 4;
            float bi[4], gs[4], bt[4], cm[4];
#pragma unroll
            for (int rg = 0; rg < 4; rg++) {
                int n = nb + rg;
                bool ok = n < Nact;
                bi[rg] = ok ? bias[n] : 0.f;
                gs[rg] = ok ? gamma[n] * BN_SCALE : 0.f;
                bt[rg] = ok ? beta[n] : 0.f;
                cm[rg] = 0.f;
            }
#pragma unroll
            for (int j = 0; j < 4; j++)
#pragma unroll
                for (int rg = 0; rg < 4; rg++) {
                    float v = fmaxf((acc[i][j][rg] + bi[rg]) * gs[rg] + bt[rg], 0.f);
                    cm[rg] = fmaxf(cm[rg], v);
                }
#pragma unroll
            for (int rg = 0; rg < 4; rg++) {
                cm[rg] = fmaxf(cm[rg], __shfl_xor(cm[rg], 1));
                cm[rg] = fmaxf(cm[rg], __shfl_xor(cm[rg], 2));
                cm[rg] = fmaxf(cm[rg], __shfl_xor(cm[rg], 4));
                cm[rg] = fmaxf(cm[rg], __shfl_xor(cm[rg], 8));
            }
            if (lr == 0) {
#pragma unroll
                for (int rg = 0; rg < 4; rg++) {
                    int n = nb + rg;
                    if (n < Nact)
                        atomicMax((unsigned*)&outF[bb * 170 + n],
                                  __float_as_uint(cm[rg]));
                }
            }
        }
    } else {
#pragma unroll
        for (int i = 0; i < NF; i++) {
            int nb = n0w + i * 16 + lq * 4;
            floatx4 bi = *(const floatx4*)(bias + nb);
            floatx4 gs = {0.f, 0.f, 0.f, 0.f}, bt = {0.f, 0.f, 0.f, 0.f};
            if (EPI == 0) {
                gs = *(const floatx4*)(gamma + nb);
                bt = *(const floatx4*)(beta + nb);
            }
#pragma unroll
            for (int j = 0; j < 4; j++) {
                int m = j * 16 + lr;
                int off = m * 1024 + ((nb * 2) ^ ((m & 7) << 4));
                sh4 pk;
                if (EPI == 1) {
                    sh4 rs = *(const sh4*)((const char*)actIn + off);
#pragma unroll
                    for (int rg = 0; rg < 4; rg++)
                        pk[rg] = f2bf(acc[i][j][rg] + bi[rg] + bf2f(rs[rg]));
                } else {
#pragma unroll
                    for (int rg = 0; rg < 4; rg++)
                        pk[rg] = f2bf(fmaxf((acc[i][j][rg] + bi[rg]) *
                                            (gs[rg] * BN_SCALE) + bt[rg], 0.f));
                }
                *(sh4*)((char*)actOut + off) = pk;
            }
        }
    }
}

__global__ __launch_bounds__(256, 1)
void mlp_k(const short* __restrict__ feats,
           const short* __restrict__ c1wT, const short* __restrict__ rwT,
           const short* __restrict__ b1wT, const short* __restrict__ b2wT,
           const short* __restrict__ b3wT,
           const float* __restrict__ c1b, const float* __restrict__ g1,
           const float* __restrict__ be1, const float* __restrict__ rb,
           const float* __restrict__ b1b, const float* __restrict__ b1g,
           const float* __restrict__ b1be,
           const float* __restrict__ b2b, const float* __restrict__ b2g,
           const float* __restrict__ b2be,
           const float* __restrict__ b3b, const float* __restrict__ b3g,
           const float* __restrict__ b3be, float* __restrict__ outF) {
    __shared__ __align__(16) short actA[64 * 512];
    __shared__ __align__(16) short actB[64 * 512];
    const int m0 = blockIdx.x * 64;

    // L1: actA = relu(bn(feats @ c1wT))    [64,576] x [512,576]
    layer<8, 0, 0, 576>(c1wT, feats, nullptr, actA, c1b, g1, be1, nullptr, m0, 512);
    __syncthreads();
    // L2: actB = actA + (actA @ rwT + rb)
    layer<8, 1, 1, 512>(rwT, nullptr, actA, actB, rb, nullptr, nullptr, nullptr, m0, 512);
    __syncthreads();
    // L3: actA = relu(bn(actB @ b1wT))
    layer<8, 0, 1, 512>(b1wT, nullptr, actB, actA, b1b, b1g, b1be, nullptr, m0, 512);
    __syncthreads();
    // L4: actB = relu(bn(actA @ b2wT))     N=256 -> NF=4 across 4 waves
    layer<4, 0, 1, 512>(b2wT, nullptr, actA, actB, b2b, b2g, b2be, nullptr, m0, 256);
    __syncthreads();
    // L5: out = colmax(relu(bn(actB @ b3wT)))  K=256, Nact=170
    layer<4, 2, 1, 256>(b3wT, nullptr, actB, nullptr, b3b, b3g, b3be, outF, m0, 170);
}

extern "C" void kernel_launch(void* const* d_in, const int* in_sizes, int n_in,
                              void* d_out, int out_size, void* d_ws, size_t ws_size,
                              hipStream_t stream) {
    const float* points = (const float*)d_in[0];
    const float* noise  = (const float*)d_in[1];
    const float* tw   = (const float*)d_in[2];
    const float* tb   = (const float*)d_in[3];
    const float* tg1  = (const float*)d_in[4];
    const float* tbt1 = (const float*)d_in[5];
    const float* td1w = (const float*)d_in[6];
    const float* td1b = (const float*)d_in[7];
    const float* tg2  = (const float*)d_in[8];
    const float* tbt2 = (const float*)d_in[9];
    const float* td2w = (const float*)d_in[10];
    const float* td2b = (const float*)d_in[11];
    const float* c1w  = (const float*)d_in[12];
    const float* c1b  = (const float*)d_in[13];
    const float* g1   = (const float*)d_in[14];
    const float* be1  = (const float*)d_in[15];
    const float* rw   = (const float*)d_in[16];
    const float* rb   = (const float*)d_in[17];
    const float* b1w  = (const float*)d_in[18];
    const float* b1b  = (const float*)d_in[19];
    const float* b1g  = (const float*)d_in[20];
    const float* b1be = (const float*)d_in[21];
    const float* b2w  = (const float*)d_in[22];
    const float* b2b  = (const float*)d_in[23];
    const float* b2g  = (const float*)d_in[24];
    const float* b2be = (const float*)d_in[25];
    const float* b3w  = (const float*)d_in[26];
    const float* b3b  = (const float*)d_in[27];
    const float* b3g  = (const float*)d_in[28];
    const float* b3be = (const float*)d_in[29];

    char* ws = (char*)d_ws;
    short* feats = (short*)(ws + OFF_FEATS);
    short* c1wT  = (short*)(ws + OFF_C1WT);
    short* rwT   = (short*)(ws + OFF_RWT);
    short* b1wT  = (short*)(ws + OFF_B1WT);
    short* b2wT  = (short*)(ws + OFF_B2WT);
    short* b3wT  = (short*)(ws + OFF_B3WT);
    float* pts   = (float*)(ws + OFF_PTS);
    float* part  = (float*)(ws + OFF_PART);
    float* outF  = (float*)d_out;

    init_k<<<313, 256, 0, stream>>>(c1w, rw, b1w, b2w, b3w,
                                    c1wT, rwT, b1wT, b2wT, b3wT,
                                    points, tw, tb, tg1, tbt1, part,
                                    outF, out_size);
    tnet2_k<<<8, 1024, 0, stream>>>(points, part, td1w, td1b, tg2, tbt2,
                                    td2w, td2b, pts);
    topk_feats_k<<<dim3(256, 8), 512, 0, stream>>>(pts, noise, feats);
    mlp_k<<<256, 256, 0, stream>>>(feats, c1wT, rwT, b1wT, b2wT, b3wT,
                                   c1b, g1, be1, rb, b1b, b1g, b1be,
                                   b2b, b2g, b2be, b3b, b3g, b3be, outF);
}